// Round 14
// baseline (915.194 us; speedup 1.0000x reference)
//
#include <hip/hip_runtime.h>

typedef unsigned short u16;
typedef unsigned int u32;
typedef __attribute__((ext_vector_type(8))) short s16x8;
typedef __attribute__((ext_vector_type(4))) float f32x4;

#define NN 10000
#define EE 200000
#define ES ((size_t)EE * 64)
#define NTILE 3125

#define DEVI __device__ __forceinline__

DEVI float us2f(u16 u) {
    union { u32 i; float f; } v; v.i = ((u32)u) << 16; return v.f;
}
DEVI u16 f2bu(float f) {
    union { float f; u32 i; } v; v.f = f;
    u32 x = v.i;
    return (u16)((x + 0x7fffu + ((x >> 16) & 1u)) >> 16);
}
DEVI float siluf(float x) { return x / (1.f + __expf(-x)); }
DEVI float sigmf(float x) { return 1.f / (1.f + __expf(-x)); }
DEVI float waveSum(float v) {
#pragma unroll
    for (int o = 32; o; o >>= 1) v += __shfl_xor(v, o);
    return v;
}
DEVI float quadSum(float v) {
#pragma unroll
    for (int o = 1; o < 16; o <<= 1) v += __shfl_xor(v, o);
    return v;
}

// ---- module-owned scratch ----
__device__ u16 g_hb[(size_t)NN * 64];
__device__ u16 g_nab[(size_t)NN * 64];
__device__ u16 g_eab[(size_t)EE * 16];
__device__ u16 g_t1[ES];
__device__ u16 g_z16[ES];
__device__ u16 g_qpi[(size_t)EE * 256];   // qp interleaved: [e][hd*64+d]
__device__ u16 g_t4[4][ES];
__device__ u16 g_M[4 * 4096];
__device__ float g_b4[(size_t)EE * 4];
__device__ float g_nr[EE];
__device__ float g_rad[EE];
__device__ float g_cdl[EE * 3];
__device__ float g_msum[NN * 64];
__device__ float g_xsum[NN * 3];
__device__ float g_nsum[NN * 3];
__device__ float g_cnt[NN];

// ---------------- prep: M, bf16 conversion, zeroing, geometry ----------------
__global__ __launch_bounds__(256) void k_prep(
    const float* __restrict__ Wq, const float* __restrict__ Wk,
    const float* __restrict__ h, const float* __restrict__ na, const float* __restrict__ ea,
    const float* __restrict__ coord, const float* __restrict__ nvecs,
    const int* __restrict__ edges)
{
    int t = blockIdx.x * 256 + threadIdx.x;
    if (t < 16384) {
        int hd = t >> 12, rem = t & 4095, k = rem >> 6, n = rem & 63;
        const float* wq = Wq + (size_t)hd * 4096 + k * 64;
        const float* wk = Wk + (size_t)hd * 4096 + n * 64;
        float acc = 0.f;
        for (int d = 0; d < 64; d++) acc += wq[d] * wk[d];
        g_M[t] = f2bu(acc);
    }
    int nt = gridDim.x * 256;
    for (int i = t; i < NN * 64; i += nt) { g_hb[i] = f2bu(h[i]); g_nab[i] = f2bu(na[i]); g_msum[i] = 0.f; }
    for (size_t i = t; i < (size_t)EE * 16; i += nt) g_eab[i] = f2bu(ea[i]);
    for (int i = t; i < NN * 3; i += nt) { g_xsum[i] = 0.f; g_nsum[i] = 0.f; }
    for (int i = t; i < NN; i += nt) g_cnt[i] = 0.f;
    for (int e = t; e < EE; e += nt) {
        int r = edges[e], c = edges[EE + e];
        float d0 = coord[r * 3 + 0] - coord[c * 3 + 0];
        float d1 = coord[r * 3 + 1] - coord[c * 3 + 1];
        float d2 = coord[r * 3 + 2] - coord[c * 3 + 2];
        float radial = d0 * d0 + d1 * d1 + d2 * d2;
        float np = nvecs[r * 3 + 0] * nvecs[c * 3 + 0]
                 + nvecs[r * 3 + 1] * nvecs[c * 3 + 1]
                 + nvecs[r * 3 + 2] * nvecs[c * 3 + 2];
        float rinv = 1.f / (sqrtf(radial) + 1e-8f);
        g_cdl[e * 3 + 0] = d0 * rinv;
        g_cdl[e * 3 + 1] = d1 * rinv;
        g_cdl[e * 3 + 2] = d2 * rinv;
        g_nr[e] = np;
        g_rad[e] = radial;
    }
}

// ---------------- chem layer1: gathered-A GEMM (bf16 sources), K=288, 2 tiles/block ----------------
__global__ __launch_bounds__(256) void k_chem1(
    const int* __restrict__ edges, const float* __restrict__ W1, const float* __restrict__ b1)
{
    __shared__ u16 sBT[64 * 296];
    int tid = threadIdx.x;
    for (int i = tid; i < 64 * 296; i += 256) {
        int n = i / 296, k = i - n * 296;
        sBT[i] = (k < 272) ? f2bu(W1[k * 64 + n]) : (u16)0;
    }
    __syncthreads();
    int lane = tid & 63, q = lane >> 4, ln = lane & 15, w = tid >> 6;
    int base = blockIdx.x * 2;
    int nt2 = (base + 1 < NTILE) ? 2 : 1;
    for (int t2 = 0; t2 < nt2; t2++) {
        int m0 = (base + t2) * 64 + w * 16;
        int e = m0 + ln;
        int r_ = edges[e], c_ = edges[EE + e];
        f32x4 acc[4];
#pragma unroll
        for (int t = 0; t < 4; t++) acc[t] = (f32x4){0.f, 0.f, 0.f, 0.f};
#pragma unroll
        for (int k0 = 0; k0 < 9; k0++) {
            int k = k0 * 32 + q * 8;
            const u16* p = nullptr;
            if (k < 64)       p = g_hb  + (size_t)r_ * 64 + k;
            else if (k < 128) p = g_hb  + (size_t)c_ * 64 + (k - 64);
            else if (k < 192) p = g_nab + (size_t)r_ * 64 + (k - 128);
            else if (k < 256) p = g_nab + (size_t)c_ * 64 + (k - 192);
            else if (k < 272) p = g_eab + (size_t)e * 16 + (k - 256);
            s16x8 af = p ? *(const s16x8*)p : (s16x8){0, 0, 0, 0, 0, 0, 0, 0};
#pragma unroll
            for (int t = 0; t < 4; t++) {
                s16x8 bf = *(const s16x8*)(&sBT[(t * 16 + ln) * 296 + k0 * 32 + q * 8]);
                acc[t] = __builtin_amdgcn_mfma_f32_16x16x32_bf16(af, bf, acc[t], 0, 0, 0);
            }
        }
#pragma unroll
        for (int t = 0; t < 4; t++) {
            float bv = b1[t * 16 + ln];
#pragma unroll
            for (int r = 0; r < 4; r++)
                g_t1[(size_t)(m0 + q * 4 + r) * 64 + t * 16 + ln] = f2bu(siluf(acc[t][r] + bv));
        }
    }
}

DEVI void stageW(u16* dst, const float* src, int tid) {
    for (int i = tid; i < 4096; i += 256) {
        int k = i >> 6, n = i & 63;
        dst[n * 72 + k] = f2bu(src[i]);
    }
}

// ---------------- MegaAB: pos(inline p1), chem -> z, b4, phiu, phix, phin, scatter, qp (fused q4) ----------------
__global__ __launch_bounds__(256) void k_megaAB(
    const float* __restrict__ chW2, const float* __restrict__ chb2,
    const float* __restrict__ pW1, const float* __restrict__ pb1,
    const float* __restrict__ posW2, const float* __restrict__ posb2,
    const float* __restrict__ shW, const float* __restrict__ shb,
    const float* __restrict__ attW, const float* __restrict__ attb,
    const float* __restrict__ Wb,
    const float* __restrict__ uW1, const float* __restrict__ ub1,
    const float* __restrict__ uW2, const float* __restrict__ ub2,
    const float* __restrict__ xW1, const float* __restrict__ xb1,
    const float* __restrict__ xW2, const float* __restrict__ xb2,
    const float* __restrict__ nW1, const float* __restrict__ nb1,
    const float* __restrict__ nW2, const float* __restrict__ nb2,
    const int* __restrict__ edges, const float* __restrict__ nvecs)
{
    __shared__ u16 sWT[6 * 64 * 72];     // 6 weight tiles; overlaid by M tiles in the qp tail
    __shared__ u16 T[4][16 * 72];
    __shared__ float sWB[256], sATT[64], sPW1[128], sPB1[64];
    u16* sCH = sWT + 0 * 4608;
    u16* sPW = sWT + 1 * 4608;
    u16* sSH = sWT + 2 * 4608;
    u16* sUW = sWT + 3 * 4608;
    u16* sXW = sWT + 4 * 4608;
    u16* sNW = sWT + 5 * 4608;
    int tid = threadIdx.x;
    stageW(sCH, chW2, tid); stageW(sPW, posW2, tid); stageW(sSH, shW, tid);
    stageW(sUW, uW1, tid);  stageW(sXW, xW1, tid);   stageW(sNW, nW1, tid);
    sWB[tid] = Wb[tid];
    if (tid < 128) sPW1[tid] = pW1[tid];
    if (tid < 64) { sATT[tid] = attW[tid]; sPB1[tid] = pb1[tid]; }
    __syncthreads();
    int lane = tid & 63, q = lane >> 4, ln = lane & 15, w = tid >> 6;
    int base = blockIdx.x * 2;
    int nt2 = (base + 1 < NTILE) ? 2 : 1;
    for (int t2 = 0; t2 < nt2; t2++) {
        int m0 = (base + t2) * 64 + w * 16;
        float np_ = g_nr[m0 + ln], rad_ = g_rad[m0 + ln];
        s16x8 p1f0, p1f1;
#pragma unroll
        for (int j = 0; j < 8; j++) {
            int k = q * 8 + j;
            p1f0[j] = (short)f2bu(siluf(sPB1[k] + np_ * sPW1[k] + rad_ * sPW1[64 + k]));
            k += 32;
            p1f1[j] = (short)f2bu(siluf(sPB1[k] + np_ * sPW1[k] + rad_ * sPW1[64 + k]));
        }
        f32x4 pacc[4];
#pragma unroll
        for (int t = 0; t < 4; t++) {
            f32x4 a = (f32x4){0,0,0,0};
            a = __builtin_amdgcn_mfma_f32_16x16x32_bf16(p1f0, *(const s16x8*)(&sPW[(t * 16 + ln) * 72 + q * 8]), a, 0, 0, 0);
            a = __builtin_amdgcn_mfma_f32_16x16x32_bf16(p1f1, *(const s16x8*)(&sPW[(t * 16 + ln) * 72 + 32 + q * 8]), a, 0, 0, 0);
            pacc[t] = a;
        }
        float posD[4][4];
#pragma unroll
        for (int t = 0; t < 4; t++) {
            float pb = posb2[t * 16 + ln];
#pragma unroll
            for (int r = 0; r < 4; r++) posD[t][r] = siluf(pacc[t][r] + pb);
        }
        f32x4 cacc[4];
#pragma unroll
        for (int t = 0; t < 4; t++) cacc[t] = (f32x4){0,0,0,0};
        {
            const u16* ar = g_t1 + (size_t)(m0 + ln) * 64;
#pragma unroll
            for (int k0 = 0; k0 < 2; k0++) {
                s16x8 af = *(const s16x8*)(ar + k0 * 32 + q * 8);
#pragma unroll
                for (int t = 0; t < 4; t++) {
                    s16x8 bf = *(const s16x8*)(&sCH[(t * 16 + ln) * 72 + k0 * 32 + q * 8]);
                    cacc[t] = __builtin_amdgcn_mfma_f32_16x16x32_bf16(af, bf, cacc[t], 0, 0, 0);
                }
            }
        }
#pragma unroll
        for (int t = 0; t < 4; t++) {
            float cb = chb2[t * 16 + ln];
#pragma unroll
            for (int r = 0; r < 4; r++)
                T[w][(q * 4 + r) * 72 + t * 16 + ln] = f2bu(siluf(cacc[t][r] + cb));
        }
        asm volatile("s_waitcnt lgkmcnt(0)" ::: "memory");
        s16x8 ca0 = *(const s16x8*)(&T[w][ln * 72 + q * 8]);
        s16x8 ca1 = *(const s16x8*)(&T[w][ln * 72 + 32 + q * 8]);
        f32x4 sacc[4];
#pragma unroll
        for (int t = 0; t < 4; t++) {
            f32x4 a = (f32x4){0,0,0,0};
            a = __builtin_amdgcn_mfma_f32_16x16x32_bf16(ca0, *(const s16x8*)(&sSH[(t * 16 + ln) * 72 + q * 8]), a, 0, 0, 0);
            a = __builtin_amdgcn_mfma_f32_16x16x32_bf16(ca1, *(const s16x8*)(&sSH[(t * 16 + ln) * 72 + 32 + q * 8]), a, 0, 0, 0);
            sacc[t] = a;
        }
        float zv[4][4];
        float part[4] = {0.f, 0.f, 0.f, 0.f};
#pragma unroll
        for (int t = 0; t < 4; t++) {
            float sb = shb[t * 16 + ln];
            float aw = sATT[t * 16 + ln];
#pragma unroll
            for (int r = 0; r < 4; r++) {
                float o = siluf(sacc[t][r] + sb) * posD[t][r];
                zv[t][r] = o;
                part[r] += o * aw;
            }
        }
        float ab = attb[0];
#pragma unroll
        for (int r = 0; r < 4; r++) {
            float sg = sigmf(quadSum(part[r]) + ab);
            size_t row = m0 + q * 4 + r;
#pragma unroll
            for (int t = 0; t < 4; t++) {
                float z = zv[t][r] * sg;
                zv[t][r] = z;
                g_z16[row * 64 + t * 16 + ln] = f2bu(z);
            }
        }
#pragma unroll
        for (int hd = 0; hd < 4; hd++) {
#pragma unroll
            for (int r = 0; r < 4; r++) {
                float p = 0.f;
#pragma unroll
                for (int t = 0; t < 4; t++) p += zv[t][r] * sWB[hd * 64 + t * 16 + ln];
                p = quadSum(p);
                if (ln == hd) g_b4[(size_t)(m0 + q * 4 + r) * 4 + hd] = p;
            }
        }
        f32x4 uacc[4];
#pragma unroll
        for (int t = 0; t < 4; t++) {
            f32x4 a = (f32x4){0,0,0,0};
            a = __builtin_amdgcn_mfma_f32_16x16x32_bf16(ca0, *(const s16x8*)(&sUW[(t * 16 + ln) * 72 + q * 8]), a, 0, 0, 0);
            a = __builtin_amdgcn_mfma_f32_16x16x32_bf16(ca1, *(const s16x8*)(&sUW[(t * 16 + ln) * 72 + 32 + q * 8]), a, 0, 0, 0);
            uacc[t] = a;
        }
        float up[4] = {0.f, 0.f, 0.f, 0.f};
#pragma unroll
        for (int t = 0; t < 4; t++) {
            float ub = ub1[t * 16 + ln];
            float w2 = uW2[t * 16 + ln];
#pragma unroll
            for (int r = 0; r < 4; r++) up[r] += siluf(uacc[t][r] + ub) * w2;
        }
        float ub2v = ub2[0];
        float pu[4];
#pragma unroll
        for (int r = 0; r < 4; r++) pu[r] = quadSum(up[r]) + ub2v;
#pragma unroll
        for (int t = 0; t < 4; t++)
#pragma unroll
            for (int r = 0; r < 4; r++)
                T[w][(q * 4 + r) * 72 + t * 16 + ln] = f2bu(posD[t][r]);
        asm volatile("s_waitcnt lgkmcnt(0)" ::: "memory");
        s16x8 pa0 = *(const s16x8*)(&T[w][ln * 72 + q * 8]);
        s16x8 pa1 = *(const s16x8*)(&T[w][ln * 72 + 32 + q * 8]);
        f32x4 xacc[4], nacc[4];
#pragma unroll
        for (int t = 0; t < 4; t++) {
            f32x4 a = (f32x4){0,0,0,0}, b = (f32x4){0,0,0,0};
            a = __builtin_amdgcn_mfma_f32_16x16x32_bf16(pa0, *(const s16x8*)(&sXW[(t * 16 + ln) * 72 + q * 8]), a, 0, 0, 0);
            a = __builtin_amdgcn_mfma_f32_16x16x32_bf16(pa1, *(const s16x8*)(&sXW[(t * 16 + ln) * 72 + 32 + q * 8]), a, 0, 0, 0);
            b = __builtin_amdgcn_mfma_f32_16x16x32_bf16(pa0, *(const s16x8*)(&sNW[(t * 16 + ln) * 72 + q * 8]), b, 0, 0, 0);
            b = __builtin_amdgcn_mfma_f32_16x16x32_bf16(pa1, *(const s16x8*)(&sNW[(t * 16 + ln) * 72 + 32 + q * 8]), b, 0, 0, 0);
            xacc[t] = a; nacc[t] = b;
        }
        float xp[4] = {0,0,0,0}, npv[4] = {0,0,0,0};
#pragma unroll
        for (int t = 0; t < 4; t++) {
            float xb = xb1[t * 16 + ln], nb = nb1[t * 16 + ln];
            float xw = xW2[t * 16 + ln], nw = nW2[t * 16 + ln];
#pragma unroll
            for (int r = 0; r < 4; r++) {
                xp[r] += siluf(xacc[t][r] + xb) * xw;
                npv[r] += siluf(nacc[t][r] + nb) * nw;
            }
        }
        float xb2v = xb2[0], nb2v = nb2[0];
#pragma unroll
        for (int r = 0; r < 4; r++) {
            float phix = quadSum(xp[r]) + xb2v;
            float phin = quadSum(npv[r]) + nb2v;
            int row = m0 + q * 4 + r;
            float tx = pu[r] * phix, tn = pu[r] * phin;
            int rr = edges[row], cc = edges[EE + row];
            if (ln < 3) {
                atomicAdd(&g_xsum[rr * 3 + ln], g_cdl[row * 3 + ln] * tx);
                atomicAdd(&g_nsum[rr * 3 + ln], nvecs[cc * 3 + ln] * tn);
            }
            if (ln == 3) atomicAdd(&g_cnt[rr], 1.f);
        }
    }
    // ---- fused q4 tail: weight tiles are dead; overlay M tiles (stride 68, 2-way-free) ----
    __syncthreads();                       // drains vmem (z writes visible) + all waves past weight use
    u16* sM = sWT;                         // [4][64*68] = 34.8 KB of the 55.3 KB region
    for (int i = tid; i < 16384; i += 256) {
        int hd = i >> 12, rem = i & 4095, k = rem >> 6, n = rem & 63;
        sM[hd * 4352 + n * 68 + k] = g_M[i];
    }
    __syncthreads();
    for (int t2 = 0; t2 < nt2; t2++) {
        int m0 = (base + t2) * 64 + w * 16;
        const u16* ar = g_z16 + (size_t)(m0 + ln) * 64;   // own rows, L1-hot
        s16x8 af0 = *(const s16x8*)(ar + q * 8);
        s16x8 af1 = *(const s16x8*)(ar + 32 + q * 8);
        for (int hd = 0; hd < 4; hd++) {
            f32x4 aM[4];
#pragma unroll
            for (int t = 0; t < 4; t++) {
                f32x4 a = (f32x4){0,0,0,0};
                a = __builtin_amdgcn_mfma_f32_16x16x32_bf16(af0, *(const s16x8*)(&sM[hd * 4352 + (t * 16 + ln) * 68 + q * 8]), a, 0, 0, 0);
                a = __builtin_amdgcn_mfma_f32_16x16x32_bf16(af1, *(const s16x8*)(&sM[hd * 4352 + (t * 16 + ln) * 68 + 32 + q * 8]), a, 0, 0, 0);
                aM[t] = a;
            }
#pragma unroll
            for (int t = 0; t < 4; t++)
#pragma unroll
                for (int r = 0; r < 4; r++)
                    g_qpi[(size_t)(m0 + q * 4 + r) * 256 + hd * 64 + t * 16 + ln] = f2bu(aM[t][r]);
        }
    }
}

// ---------------- attention: MFMA scores, LDS-fed PV, 2-deep klist prefetch ----------------
__global__ __launch_bounds__(256) void k_attn2(const int* __restrict__ klist)
{
    __shared__ __align__(16) float sA[4][4][16];
    __shared__ u16 zT[4][16 * 72];
    int tid = threadIdx.x;
    int w = tid >> 6, lane = tid & 63, q = lane >> 4, ln = lane & 15;
    int wid = blockIdx.x * 4 + w;
    int nw = gridDim.x * 4;
    u16* zw = zT[w];
    int e0 = wid;
    int kv0 = (lane < 32) ? klist[(size_t)e0 * 32 + lane] : -1;
    int e1 = e0 + nw;
    int kv1 = (e1 < EE && lane < 32) ? klist[(size_t)e1 * 32 + lane] : -1;
    int ij0 = __shfl(kv0, ln);
    s16x8 za0 = {0,0,0,0,0,0,0,0}, za1 = {0,0,0,0,0,0,0,0};
    if (ij0 >= 0) {
        const u16* zr = g_z16 + (size_t)ij0 * 64;
        za0 = *(const s16x8*)(zr + q * 8);
        za1 = *(const s16x8*)(zr + 32 + q * 8);
    }
    s16x8 qb0 = {0,0,0,0,0,0,0,0}, qb1 = {0,0,0,0,0,0,0,0};
    if (ln < 4) {
        const u16* qr = g_qpi + (size_t)e0 * 256 + ln * 64;
        qb0 = *(const s16x8*)(qr + q * 8);
        qb1 = *(const s16x8*)(qr + 32 + q * 8);
    }
    while (true) {
        int e2 = e1 + nw;
        int kv2 = (e2 < EE && lane < 32) ? klist[(size_t)e2 * 32 + lane] : -1;
        f32x4 sc = (f32x4){0.f, 0.f, 0.f, 0.f};
        sc = __builtin_amdgcn_mfma_f32_16x16x32_bf16(za0, qb0, sc, 0, 0, 0);
        sc = __builtin_amdgcn_mfma_f32_16x16x32_bf16(za1, qb1, sc, 0, 0, 0);
        *(s16x8*)(&zw[ln * 72 + q * 8]) = za0;
        *(s16x8*)(&zw[ln * 72 + 32 + q * 8]) = za1;
        int ij1 = __shfl(kv1, ln);
        s16x8 nza0 = {0,0,0,0,0,0,0,0}, nza1 = {0,0,0,0,0,0,0,0};
        if (ij1 >= 0) {
            const u16* zr = g_z16 + (size_t)ij1 * 64;
            nza0 = *(const s16x8*)(zr + q * 8);
            nza1 = *(const s16x8*)(zr + 32 + q * 8);
        }
        s16x8 nqb0 = {0,0,0,0,0,0,0,0}, nqb1 = {0,0,0,0,0,0,0,0};
        if (e1 < EE && ln < 4) {
            const u16* qr = g_qpi + (size_t)e1 * 256 + ln * 64;
            nqb0 = *(const s16x8*)(qr + q * 8);
            nqb1 = *(const s16x8*)(qr + 32 + q * 8);
        }
        float s[4];
#pragma unroll
        for (int r = 0; r < 4; r++) {
            int j = q * 4 + r;
            int ijj = __shfl(kv0, j);
            int jj = __shfl(kv0, 16 + j);
            float bvl = (ijj >= 0 && ln < 4) ? g_b4[(size_t)jj * 4 + ln] : 0.f;
            s[r] = (ijj >= 0) ? (0.125f * sc[r] + bvl) : 0.f;
        }
        float mx = fmaxf(fmaxf(s[0], s[1]), fmaxf(s[2], s[3]));
        mx = fmaxf(mx, __shfl_xor(mx, 16));
        mx = fmaxf(mx, __shfl_xor(mx, 32));
        float ex[4], ps = 0.f;
#pragma unroll
        for (int r = 0; r < 4; r++) { ex[r] = __expf(s[r] - mx); ps += ex[r]; }
        ps += __shfl_xor(ps, 16);
        ps += __shfl_xor(ps, 32);
        float inv = 1.f / ps;
        if (ln < 4)
            *(f32x4*)&sA[w][ln][q * 4] = (f32x4){ex[0] * inv, ex[1] * inv, ex[2] * inv, ex[3] * inv};
        asm volatile("s_waitcnt lgkmcnt(0)" ::: "memory");
        float t0 = 0.f, t1 = 0.f, t2 = 0.f, t3 = 0.f;
#pragma unroll
        for (int j4 = 0; j4 < 4; j4++) {
            f32x4 a0 = *(const f32x4*)&sA[w][0][j4 * 4];
            f32x4 a1 = *(const f32x4*)&sA[w][1][j4 * 4];
            f32x4 a2 = *(const f32x4*)&sA[w][2][j4 * 4];
            f32x4 a3 = *(const f32x4*)&sA[w][3][j4 * 4];
#pragma unroll
            for (int r = 0; r < 4; r++) {
                float zz = us2f(zw[(j4 * 4 + r) * 72 + lane]);
                t0 += a0[r] * zz; t1 += a1[r] * zz; t2 += a2[r] * zz; t3 += a3[r] * zz;
            }
        }
        size_t ob = (size_t)e0 * 64 + lane;
        g_t4[0][ob] = f2bu(t0);
        g_t4[1][ob] = f2bu(t1);
        g_t4[2][ob] = f2bu(t2);
        g_t4[3][ob] = f2bu(t3);
        if (e1 >= EE) break;
        e0 = e1; kv0 = kv1;
        e1 = e2; kv1 = kv2;
        za0 = nza0; za1 = nza1; qb0 = nqb0; qb1 = nqb1;
    }
}

// ---------------- fused heads: u=(t@Wv)*sigm(z@Wg+bg); m=Σ_hd u@oW_hd; single tile ----------------
__global__ __launch_bounds__(256) void k_us(
    const float* __restrict__ Wv, const float* __restrict__ Wg, const float* __restrict__ bg,
    const float* __restrict__ oW, const int* __restrict__ edges)
{
    __shared__ u16 sV[64 * 72], sO[64 * 72], sG[64 * 72];
    __shared__ u16 sU[4][16 * 72];
    int tid = threadIdx.x;
    int lane = tid & 63, q = lane >> 4, ln = lane & 15, w = tid >> 6;
    int m0 = blockIdx.x * 64 + w * 16;
    const u16* zr = g_z16 + (size_t)(m0 + ln) * 64;
    s16x8 za[2];
    za[0] = *(const s16x8*)(zr + q * 8);
    za[1] = *(const s16x8*)(zr + 32 + q * 8);
    f32x4 macc[4];
#pragma unroll
    for (int t = 0; t < 4; t++) macc[t] = (f32x4){0,0,0,0};
    for (int hd = 0; hd < 4; hd++) {
        if (hd) __syncthreads();
        stageW(sV, Wv + (size_t)hd * 4096, tid);
        stageW(sO, oW + (size_t)hd * 4096, tid);
        stageW(sG, Wg + (size_t)hd * 4096, tid);
        __syncthreads();
        f32x4 vacc[4], gacc[4];
#pragma unroll
        for (int t = 0; t < 4; t++) { vacc[t] = (f32x4){0,0,0,0}; gacc[t] = (f32x4){0,0,0,0}; }
        const u16* ar = &g_t4[hd][(size_t)(m0 + ln) * 64];
#pragma unroll
        for (int k0 = 0; k0 < 2; k0++) {
            s16x8 af = *(const s16x8*)(ar + k0 * 32 + q * 8);
#pragma unroll
            for (int t = 0; t < 4; t++) {
                vacc[t] = __builtin_amdgcn_mfma_f32_16x16x32_bf16(
                    af, *(const s16x8*)(&sV[(t * 16 + ln) * 72 + k0 * 32 + q * 8]), vacc[t], 0, 0, 0);
                gacc[t] = __builtin_amdgcn_mfma_f32_16x16x32_bf16(
                    za[k0], *(const s16x8*)(&sG[(t * 16 + ln) * 72 + k0 * 32 + q * 8]), gacc[t], 0, 0, 0);
            }
        }
#pragma unroll
        for (int t = 0; t < 4; t++) {
            float bb = bg[hd * 64 + t * 16 + ln];
#pragma unroll
            for (int r = 0; r < 4; r++) {
                float u = vacc[t][r] * sigmf(gacc[t][r] + bb);
                sU[w][(q * 4 + r) * 72 + t * 16 + ln] = f2bu(u);
            }
        }
        asm volatile("s_waitcnt lgkmcnt(0)" ::: "memory");
#pragma unroll
        for (int k0 = 0; k0 < 2; k0++) {
            s16x8 af = *(const s16x8*)(&sU[w][ln * 72 + k0 * 32 + q * 8]);
#pragma unroll
            for (int t = 0; t < 4; t++) {
                macc[t] = __builtin_amdgcn_mfma_f32_16x16x32_bf16(
                    af, *(const s16x8*)(&sO[(t * 16 + ln) * 72 + k0 * 32 + q * 8]), macc[t], 0, 0, 0);
            }
        }
    }
#pragma unroll
    for (int r = 0; r < 4; r++) {
        int dst = edges[m0 + q * 4 + r] * 64;
#pragma unroll
        for (int t = 0; t < 4; t++) atomicAdd(&g_msum[dst + t * 16 + ln], macc[t][r]);
    }
}

// ---------------- node finalize ----------------
__global__ __launch_bounds__(256) void k_node(
    const float* __restrict__ h, const float* __restrict__ na,
    const float* __restrict__ coord, const float* __restrict__ nvecs,
    const float* __restrict__ icoord, const float* __restrict__ invecs,
    const float* __restrict__ ob,
    const float* __restrict__ W1, const float* __restrict__ b1,
    const float* __restrict__ W2, const float* __restrict__ b2,
    float* __restrict__ out)
{
    __shared__ u16 sW1[192 * 64], sW2[4096];
    __shared__ float sb1[64], sb2[64];
    int tid = threadIdx.x;
    for (int i = tid; i < 192 * 64; i += 256) sW1[i] = f2bu(W1[i]);
    for (int i = tid; i < 4096; i += 256) sW2[i] = f2bu(W2[i]);
    if (tid < 64) { sb1[tid] = b1[tid]; sb2[tid] = b2[tid]; }
    __syncthreads();
    size_t coff = (size_t)NN * 64;
    size_t noff = coff + (size_t)NN * 3;
    int lane = tid & 63;
    int wid = blockIdx.x * 4 + (tid >> 6);
    int nw = gridDim.x * 4;
    for (int n = wid; n < NN; n += nw) {
        float craw = g_cnt[n];
        float rinv = 1.f / fmaxf(craw, 1.f);
        float hl = h[(size_t)n * 64 + lane];
        float al = na[(size_t)n * 64 + lane];
        float obv = (craw > 0.f) ? ob[lane] : 0.f;
        float ml = g_msum[n * 64 + lane] * rinv + obv;
        float acc = sb1[lane];
        for (int i = 0; i < 64; i++) acc += __shfl(hl, i) * us2f(sW1[i * 64 + lane]);
        for (int i = 0; i < 64; i++) acc += __shfl(al, i) * us2f(sW1[(64 + i) * 64 + lane]);
        for (int i = 0; i < 64; i++) acc += __shfl(ml, i) * us2f(sW1[(128 + i) * 64 + lane]);
        float t = siluf(acc);
        float a2 = sb2[lane];
        for (int i = 0; i < 64; i++) a2 += __shfl(t, i) * us2f(sW2[i * 64 + lane]);
        out[(size_t)n * 64 + lane] = 0.2f * hl + 0.8f * a2;
        if (lane < 3) {
            out[coff + n * 3 + lane] = 0.2f * icoord[n * 3 + lane] + 0.8f * coord[n * 3 + lane]
                                       + g_xsum[n * 3 + lane] * rinv;
        }
        float nl = (lane < 3)
            ? (0.2f * invecs[n * 3 + lane] + 0.8f * nvecs[n * 3 + lane] + g_nsum[n * 3 + lane] * rinv)
            : 0.f;
        float nn = sqrtf(waveSum(nl * nl)) + 1e-8f;
        if (lane < 3) out[noff + n * 3 + lane] = nl / nn;
    }
}

extern "C" void kernel_launch(void* const* d_in, const int* in_sizes, int n_in,
                              void* d_out, int out_size, void* d_ws, size_t ws_size,
                              hipStream_t stream)
{
    const int* edges = (const int*)d_in[43];
    const int* klist = (const int*)d_in[44];
    auto F = [&](int i) { return (const float*)d_in[i]; };

    k_prep<<<512, 256, 0, stream>>>(F(19), F(20), F(0), F(4), F(3), F(1), F(2), edges);
    k_chem1<<<1563, 256, 0, stream>>>(edges, F(7), F(8));
    k_megaAB<<<1563, 256, 0, stream>>>(F(9), F(10), F(11), F(12), F(13), F(14),
                                       F(15), F(16), F(17), F(18), F(22),
                                       F(27), F(28), F(29), F(30),
                                       F(31), F(32), F(33), F(34),
                                       F(35), F(36), F(37), F(38),
                                       edges, F(2));
    k_attn2<<<2048, 256, 0, stream>>>(klist);
    k_us<<<3125, 256, 0, stream>>>(F(21), F(23), F(24), F(25), edges);
    k_node<<<640, 256, 0, stream>>>(F(0), F(4), F(1), F(2), F(5), F(6), F(26),
                                    F(39), F(40), F(41), F(42), (float*)d_out);
}

// Round 15
// 891.725 us; speedup vs baseline: 1.0263x; 1.0263x over previous
//
#include <hip/hip_runtime.h>

typedef unsigned short u16;
typedef unsigned int u32;
typedef __attribute__((ext_vector_type(8))) short s16x8;
typedef __attribute__((ext_vector_type(4))) float f32x4;

#define NN 10000
#define EE 200000
#define ES ((size_t)EE * 64)
#define NTILE 3125

#define DEVI __device__ __forceinline__

DEVI float us2f(u16 u) {
    union { u32 i; float f; } v; v.i = ((u32)u) << 16; return v.f;
}
DEVI u16 f2bu(float f) {
    union { float f; u32 i; } v; v.f = f;
    u32 x = v.i;
    return (u16)((x + 0x7fffu + ((x >> 16) & 1u)) >> 16);
}
DEVI float siluf(float x) { return x / (1.f + __expf(-x)); }
DEVI float sigmf(float x) { return 1.f / (1.f + __expf(-x)); }
DEVI float waveSum(float v) {
#pragma unroll
    for (int o = 32; o; o >>= 1) v += __shfl_xor(v, o);
    return v;
}
DEVI float quadSum(float v) {
#pragma unroll
    for (int o = 1; o < 16; o <<= 1) v += __shfl_xor(v, o);
    return v;
}

// ---- module-owned scratch ----
__device__ u16 g_hb[(size_t)NN * 64];
__device__ u16 g_nab[(size_t)NN * 64];
__device__ u16 g_eab[(size_t)EE * 16];
__device__ u16 g_t1[ES];
__device__ u16 g_z16[ES];
__device__ u16 g_qpi[(size_t)EE * 256];   // qp interleaved: [e][hd*64+d]
__device__ u16 g_t4[4][ES];
__device__ u16 g_M[4 * 4096];
__device__ float g_b4[(size_t)EE * 4];
__device__ float g_nr[EE];
__device__ float g_rad[EE];
__device__ float g_cdl[EE * 3];
__device__ float g_msum[NN * 64];
__device__ float g_xsum[NN * 3];
__device__ float g_nsum[NN * 3];
__device__ float g_cnt[NN];

// ---------------- prep: M, bf16 conversion, zeroing, geometry ----------------
__global__ __launch_bounds__(256) void k_prep(
    const float* __restrict__ Wq, const float* __restrict__ Wk,
    const float* __restrict__ h, const float* __restrict__ na, const float* __restrict__ ea,
    const float* __restrict__ coord, const float* __restrict__ nvecs,
    const int* __restrict__ edges)
{
    int t = blockIdx.x * 256 + threadIdx.x;
    if (t < 16384) {
        int hd = t >> 12, rem = t & 4095, k = rem >> 6, n = rem & 63;
        const float* wq = Wq + (size_t)hd * 4096 + k * 64;
        const float* wk = Wk + (size_t)hd * 4096 + n * 64;
        float acc = 0.f;
        for (int d = 0; d < 64; d++) acc += wq[d] * wk[d];
        g_M[t] = f2bu(acc);
    }
    int nt = gridDim.x * 256;
    for (int i = t; i < NN * 64; i += nt) { g_hb[i] = f2bu(h[i]); g_nab[i] = f2bu(na[i]); g_msum[i] = 0.f; }
    for (size_t i = t; i < (size_t)EE * 16; i += nt) g_eab[i] = f2bu(ea[i]);
    for (int i = t; i < NN * 3; i += nt) { g_xsum[i] = 0.f; g_nsum[i] = 0.f; }
    for (int i = t; i < NN; i += nt) g_cnt[i] = 0.f;
    for (int e = t; e < EE; e += nt) {
        int r = edges[e], c = edges[EE + e];
        float d0 = coord[r * 3 + 0] - coord[c * 3 + 0];
        float d1 = coord[r * 3 + 1] - coord[c * 3 + 1];
        float d2 = coord[r * 3 + 2] - coord[c * 3 + 2];
        float radial = d0 * d0 + d1 * d1 + d2 * d2;
        float np = nvecs[r * 3 + 0] * nvecs[c * 3 + 0]
                 + nvecs[r * 3 + 1] * nvecs[c * 3 + 1]
                 + nvecs[r * 3 + 2] * nvecs[c * 3 + 2];
        float rinv = 1.f / (sqrtf(radial) + 1e-8f);
        g_cdl[e * 3 + 0] = d0 * rinv;
        g_cdl[e * 3 + 1] = d1 * rinv;
        g_cdl[e * 3 + 2] = d2 * rinv;
        g_nr[e] = np;
        g_rad[e] = radial;
    }
}

// ---------------- chem layer1: gathered-A GEMM (bf16 sources), K=288, 2 tiles/block ----------------
__global__ __launch_bounds__(256) void k_chem1(
    const int* __restrict__ edges, const float* __restrict__ W1, const float* __restrict__ b1)
{
    __shared__ u16 sBT[64 * 296];
    int tid = threadIdx.x;
    for (int i = tid; i < 64 * 296; i += 256) {
        int n = i / 296, k = i - n * 296;
        sBT[i] = (k < 272) ? f2bu(W1[k * 64 + n]) : (u16)0;
    }
    __syncthreads();
    int lane = tid & 63, q = lane >> 4, ln = lane & 15, w = tid >> 6;
    int base = blockIdx.x * 2;
    int nt2 = (base + 1 < NTILE) ? 2 : 1;
    for (int t2 = 0; t2 < nt2; t2++) {
        int m0 = (base + t2) * 64 + w * 16;
        int e = m0 + ln;
        int r_ = edges[e], c_ = edges[EE + e];
        f32x4 acc[4];
#pragma unroll
        for (int t = 0; t < 4; t++) acc[t] = (f32x4){0.f, 0.f, 0.f, 0.f};
#pragma unroll
        for (int k0 = 0; k0 < 9; k0++) {
            int k = k0 * 32 + q * 8;
            const u16* p = nullptr;
            if (k < 64)       p = g_hb  + (size_t)r_ * 64 + k;
            else if (k < 128) p = g_hb  + (size_t)c_ * 64 + (k - 64);
            else if (k < 192) p = g_nab + (size_t)r_ * 64 + (k - 128);
            else if (k < 256) p = g_nab + (size_t)c_ * 64 + (k - 192);
            else if (k < 272) p = g_eab + (size_t)e * 16 + (k - 256);
            s16x8 af = p ? *(const s16x8*)p : (s16x8){0, 0, 0, 0, 0, 0, 0, 0};
#pragma unroll
            for (int t = 0; t < 4; t++) {
                s16x8 bf = *(const s16x8*)(&sBT[(t * 16 + ln) * 296 + k0 * 32 + q * 8]);
                acc[t] = __builtin_amdgcn_mfma_f32_16x16x32_bf16(af, bf, acc[t], 0, 0, 0);
            }
        }
#pragma unroll
        for (int t = 0; t < 4; t++) {
            float bv = b1[t * 16 + ln];
#pragma unroll
            for (int r = 0; r < 4; r++)
                g_t1[(size_t)(m0 + q * 4 + r) * 64 + t * 16 + ln] = f2bu(siluf(acc[t][r] + bv));
        }
    }
}

DEVI void stageW(u16* dst, const float* src, int tid) {
    for (int i = tid; i < 4096; i += 256) {
        int k = i >> 6, n = i & 63;
        dst[n * 72 + k] = f2bu(src[i]);
    }
}

// ---------------- MegaAB: pos(inline p1), chem -> z, b4, phiu, phix, phin, scatter; 2 tiles ----------------
__global__ __launch_bounds__(256) void k_megaAB(
    const float* __restrict__ chW2, const float* __restrict__ chb2,
    const float* __restrict__ pW1, const float* __restrict__ pb1,
    const float* __restrict__ posW2, const float* __restrict__ posb2,
    const float* __restrict__ shW, const float* __restrict__ shb,
    const float* __restrict__ attW, const float* __restrict__ attb,
    const float* __restrict__ Wb,
    const float* __restrict__ uW1, const float* __restrict__ ub1,
    const float* __restrict__ uW2, const float* __restrict__ ub2,
    const float* __restrict__ xW1, const float* __restrict__ xb1,
    const float* __restrict__ xW2, const float* __restrict__ xb2,
    const float* __restrict__ nW1, const float* __restrict__ nb1,
    const float* __restrict__ nW2, const float* __restrict__ nb2,
    const int* __restrict__ edges, const float* __restrict__ nvecs)
{
    __shared__ u16 sCH[64 * 72], sPW[64 * 72], sSH[64 * 72], sUW[64 * 72], sXW[64 * 72], sNW[64 * 72];
    __shared__ u16 T[4][16 * 72];
    __shared__ float sWB[256], sATT[64], sPW1[128], sPB1[64];
    int tid = threadIdx.x;
    stageW(sCH, chW2, tid); stageW(sPW, posW2, tid); stageW(sSH, shW, tid);
    stageW(sUW, uW1, tid);  stageW(sXW, xW1, tid);   stageW(sNW, nW1, tid);
    sWB[tid] = Wb[tid];
    if (tid < 128) sPW1[tid] = pW1[tid];
    if (tid < 64) { sATT[tid] = attW[tid]; sPB1[tid] = pb1[tid]; }
    __syncthreads();
    int lane = tid & 63, q = lane >> 4, ln = lane & 15, w = tid >> 6;
    int base = blockIdx.x * 2;
    int nt2 = (base + 1 < NTILE) ? 2 : 1;
    for (int t2 = 0; t2 < nt2; t2++) {
        int m0 = (base + t2) * 64 + w * 16;
        float np_ = g_nr[m0 + ln], rad_ = g_rad[m0 + ln];
        s16x8 p1f0, p1f1;
#pragma unroll
        for (int j = 0; j < 8; j++) {
            int k = q * 8 + j;
            p1f0[j] = (short)f2bu(siluf(sPB1[k] + np_ * sPW1[k] + rad_ * sPW1[64 + k]));
            k += 32;
            p1f1[j] = (short)f2bu(siluf(sPB1[k] + np_ * sPW1[k] + rad_ * sPW1[64 + k]));
        }
        f32x4 pacc[4];
#pragma unroll
        for (int t = 0; t < 4; t++) {
            f32x4 a = (f32x4){0,0,0,0};
            a = __builtin_amdgcn_mfma_f32_16x16x32_bf16(p1f0, *(const s16x8*)(&sPW[(t * 16 + ln) * 72 + q * 8]), a, 0, 0, 0);
            a = __builtin_amdgcn_mfma_f32_16x16x32_bf16(p1f1, *(const s16x8*)(&sPW[(t * 16 + ln) * 72 + 32 + q * 8]), a, 0, 0, 0);
            pacc[t] = a;
        }
        float posD[4][4];
#pragma unroll
        for (int t = 0; t < 4; t++) {
            float pb = posb2[t * 16 + ln];
#pragma unroll
            for (int r = 0; r < 4; r++) posD[t][r] = siluf(pacc[t][r] + pb);
        }
        f32x4 cacc[4];
#pragma unroll
        for (int t = 0; t < 4; t++) cacc[t] = (f32x4){0,0,0,0};
        {
            const u16* ar = g_t1 + (size_t)(m0 + ln) * 64;
#pragma unroll
            for (int k0 = 0; k0 < 2; k0++) {
                s16x8 af = *(const s16x8*)(ar + k0 * 32 + q * 8);
#pragma unroll
                for (int t = 0; t < 4; t++) {
                    s16x8 bf = *(const s16x8*)(&sCH[(t * 16 + ln) * 72 + k0 * 32 + q * 8]);
                    cacc[t] = __builtin_amdgcn_mfma_f32_16x16x32_bf16(af, bf, cacc[t], 0, 0, 0);
                }
            }
        }
#pragma unroll
        for (int t = 0; t < 4; t++) {
            float cb = chb2[t * 16 + ln];
#pragma unroll
            for (int r = 0; r < 4; r++)
                T[w][(q * 4 + r) * 72 + t * 16 + ln] = f2bu(siluf(cacc[t][r] + cb));
        }
        asm volatile("s_waitcnt lgkmcnt(0)" ::: "memory");
        s16x8 ca0 = *(const s16x8*)(&T[w][ln * 72 + q * 8]);
        s16x8 ca1 = *(const s16x8*)(&T[w][ln * 72 + 32 + q * 8]);
        f32x4 sacc[4];
#pragma unroll
        for (int t = 0; t < 4; t++) {
            f32x4 a = (f32x4){0,0,0,0};
            a = __builtin_amdgcn_mfma_f32_16x16x32_bf16(ca0, *(const s16x8*)(&sSH[(t * 16 + ln) * 72 + q * 8]), a, 0, 0, 0);
            a = __builtin_amdgcn_mfma_f32_16x16x32_bf16(ca1, *(const s16x8*)(&sSH[(t * 16 + ln) * 72 + 32 + q * 8]), a, 0, 0, 0);
            sacc[t] = a;
        }
        float zv[4][4];
        float part[4] = {0.f, 0.f, 0.f, 0.f};
#pragma unroll
        for (int t = 0; t < 4; t++) {
            float sb = shb[t * 16 + ln];
            float aw = sATT[t * 16 + ln];
#pragma unroll
            for (int r = 0; r < 4; r++) {
                float o = siluf(sacc[t][r] + sb) * posD[t][r];
                zv[t][r] = o;
                part[r] += o * aw;
            }
        }
        float ab = attb[0];
#pragma unroll
        for (int r = 0; r < 4; r++) {
            float sg = sigmf(quadSum(part[r]) + ab);
            size_t row = m0 + q * 4 + r;
#pragma unroll
            for (int t = 0; t < 4; t++) {
                float z = zv[t][r] * sg;
                zv[t][r] = z;
                g_z16[row * 64 + t * 16 + ln] = f2bu(z);
            }
        }
#pragma unroll
        for (int hd = 0; hd < 4; hd++) {
#pragma unroll
            for (int r = 0; r < 4; r++) {
                float p = 0.f;
#pragma unroll
                for (int t = 0; t < 4; t++) p += zv[t][r] * sWB[hd * 64 + t * 16 + ln];
                p = quadSum(p);
                if (ln == hd) g_b4[(size_t)(m0 + q * 4 + r) * 4 + hd] = p;
            }
        }
        f32x4 uacc[4];
#pragma unroll
        for (int t = 0; t < 4; t++) {
            f32x4 a = (f32x4){0,0,0,0};
            a = __builtin_amdgcn_mfma_f32_16x16x32_bf16(ca0, *(const s16x8*)(&sUW[(t * 16 + ln) * 72 + q * 8]), a, 0, 0, 0);
            a = __builtin_amdgcn_mfma_f32_16x16x32_bf16(ca1, *(const s16x8*)(&sUW[(t * 16 + ln) * 72 + 32 + q * 8]), a, 0, 0, 0);
            uacc[t] = a;
        }
        float up[4] = {0.f, 0.f, 0.f, 0.f};
#pragma unroll
        for (int t = 0; t < 4; t++) {
            float ub = ub1[t * 16 + ln];
            float w2 = uW2[t * 16 + ln];
#pragma unroll
            for (int r = 0; r < 4; r++) up[r] += siluf(uacc[t][r] + ub) * w2;
        }
        float ub2v = ub2[0];
        float pu[4];
#pragma unroll
        for (int r = 0; r < 4; r++) pu[r] = quadSum(up[r]) + ub2v;
#pragma unroll
        for (int t = 0; t < 4; t++)
#pragma unroll
            for (int r = 0; r < 4; r++)
                T[w][(q * 4 + r) * 72 + t * 16 + ln] = f2bu(posD[t][r]);
        asm volatile("s_waitcnt lgkmcnt(0)" ::: "memory");
        s16x8 pa0 = *(const s16x8*)(&T[w][ln * 72 + q * 8]);
        s16x8 pa1 = *(const s16x8*)(&T[w][ln * 72 + 32 + q * 8]);
        f32x4 xacc[4], nacc[4];
#pragma unroll
        for (int t = 0; t < 4; t++) {
            f32x4 a = (f32x4){0,0,0,0}, b = (f32x4){0,0,0,0};
            a = __builtin_amdgcn_mfma_f32_16x16x32_bf16(pa0, *(const s16x8*)(&sXW[(t * 16 + ln) * 72 + q * 8]), a, 0, 0, 0);
            a = __builtin_amdgcn_mfma_f32_16x16x32_bf16(pa1, *(const s16x8*)(&sXW[(t * 16 + ln) * 72 + 32 + q * 8]), a, 0, 0, 0);
            b = __builtin_amdgcn_mfma_f32_16x16x32_bf16(pa0, *(const s16x8*)(&sNW[(t * 16 + ln) * 72 + q * 8]), b, 0, 0, 0);
            b = __builtin_amdgcn_mfma_f32_16x16x32_bf16(pa1, *(const s16x8*)(&sNW[(t * 16 + ln) * 72 + 32 + q * 8]), b, 0, 0, 0);
            xacc[t] = a; nacc[t] = b;
        }
        float xp[4] = {0,0,0,0}, npv[4] = {0,0,0,0};
#pragma unroll
        for (int t = 0; t < 4; t++) {
            float xb = xb1[t * 16 + ln], nb = nb1[t * 16 + ln];
            float xw = xW2[t * 16 + ln], nw = nW2[t * 16 + ln];
#pragma unroll
            for (int r = 0; r < 4; r++) {
                xp[r] += siluf(xacc[t][r] + xb) * xw;
                npv[r] += siluf(nacc[t][r] + nb) * nw;
            }
        }
        float xb2v = xb2[0], nb2v = nb2[0];
#pragma unroll
        for (int r = 0; r < 4; r++) {
            float phix = quadSum(xp[r]) + xb2v;
            float phin = quadSum(npv[r]) + nb2v;
            int row = m0 + q * 4 + r;
            float tx = pu[r] * phix, tn = pu[r] * phin;
            int rr = edges[row], cc = edges[EE + row];
            if (ln < 3) {
                atomicAdd(&g_xsum[rr * 3 + ln], g_cdl[row * 3 + ln] * tx);
                atomicAdd(&g_nsum[rr * 3 + ln], nvecs[cc * 3 + ln] * tn);
            }
            if (ln == 3) atomicAdd(&g_cnt[rr], 1.f);
        }
    }
}

// ---------------- qp: all 4 heads, interleaved [e][hd*64+d] output, 2 tiles/block ----------------
__global__ __launch_bounds__(256) void k_q4()
{
    __shared__ u16 sM[4][64 * 72];
    int tid = threadIdx.x;
    for (int i = tid; i < 16384; i += 256) {
        int hd = i >> 12, rem = i & 4095, k = rem >> 6, n = rem & 63;
        sM[hd][n * 72 + k] = g_M[i];
    }
    __syncthreads();
    int lane = tid & 63, q = lane >> 4, ln = lane & 15, w = tid >> 6;
    int base = blockIdx.x * 2;
    int nt2 = (base + 1 < NTILE) ? 2 : 1;
    for (int t2 = 0; t2 < nt2; t2++) {
        int m0 = (base + t2) * 64 + w * 16;
        const u16* ar = g_z16 + (size_t)(m0 + ln) * 64;
        s16x8 af0 = *(const s16x8*)(ar + q * 8);
        s16x8 af1 = *(const s16x8*)(ar + 32 + q * 8);
        for (int hd = 0; hd < 4; hd++) {
            f32x4 aM[4];
#pragma unroll
            for (int t = 0; t < 4; t++) {
                f32x4 a = (f32x4){0,0,0,0};
                a = __builtin_amdgcn_mfma_f32_16x16x32_bf16(af0, *(const s16x8*)(&sM[hd][(t * 16 + ln) * 72 + q * 8]), a, 0, 0, 0);
                a = __builtin_amdgcn_mfma_f32_16x16x32_bf16(af1, *(const s16x8*)(&sM[hd][(t * 16 + ln) * 72 + 32 + q * 8]), a, 0, 0, 0);
                aM[t] = a;
            }
#pragma unroll
            for (int t = 0; t < 4; t++)
#pragma unroll
                for (int r = 0; r < 4; r++)
                    g_qpi[(size_t)(m0 + q * 4 + r) * 256 + hd * 64 + t * 16 + ln] = f2bu(aM[t][r]);
        }
    }
}

// ---------------- attention: MFMA scores, LDS-fed PV, 2-deep klist prefetch ----------------
__global__ __launch_bounds__(256) void k_attn2(const int* __restrict__ klist)
{
    __shared__ __align__(16) float sA[4][4][16];
    __shared__ u16 zT[4][16 * 72];
    int tid = threadIdx.x;
    int w = tid >> 6, lane = tid & 63, q = lane >> 4, ln = lane & 15;
    int wid = blockIdx.x * 4 + w;
    int nw = gridDim.x * 4;
    u16* zw = zT[w];
    int e0 = wid;
    int kv0 = (lane < 32) ? klist[(size_t)e0 * 32 + lane] : -1;
    int e1 = e0 + nw;
    int kv1 = (e1 < EE && lane < 32) ? klist[(size_t)e1 * 32 + lane] : -1;
    int ij0 = __shfl(kv0, ln);
    s16x8 za0 = {0,0,0,0,0,0,0,0}, za1 = {0,0,0,0,0,0,0,0};
    if (ij0 >= 0) {
        const u16* zr = g_z16 + (size_t)ij0 * 64;
        za0 = *(const s16x8*)(zr + q * 8);
        za1 = *(const s16x8*)(zr + 32 + q * 8);
    }
    s16x8 qb0 = {0,0,0,0,0,0,0,0}, qb1 = {0,0,0,0,0,0,0,0};
    if (ln < 4) {
        const u16* qr = g_qpi + (size_t)e0 * 256 + ln * 64;
        qb0 = *(const s16x8*)(qr + q * 8);
        qb1 = *(const s16x8*)(qr + 32 + q * 8);
    }
    while (true) {
        int e2 = e1 + nw;
        int kv2 = (e2 < EE && lane < 32) ? klist[(size_t)e2 * 32 + lane] : -1;
        f32x4 sc = (f32x4){0.f, 0.f, 0.f, 0.f};
        sc = __builtin_amdgcn_mfma_f32_16x16x32_bf16(za0, qb0, sc, 0, 0, 0);
        sc = __builtin_amdgcn_mfma_f32_16x16x32_bf16(za1, qb1, sc, 0, 0, 0);
        *(s16x8*)(&zw[ln * 72 + q * 8]) = za0;
        *(s16x8*)(&zw[ln * 72 + 32 + q * 8]) = za1;
        int ij1 = __shfl(kv1, ln);
        s16x8 nza0 = {0,0,0,0,0,0,0,0}, nza1 = {0,0,0,0,0,0,0,0};
        if (ij1 >= 0) {
            const u16* zr = g_z16 + (size_t)ij1 * 64;
            nza0 = *(const s16x8*)(zr + q * 8);
            nza1 = *(const s16x8*)(zr + 32 + q * 8);
        }
        s16x8 nqb0 = {0,0,0,0,0,0,0,0}, nqb1 = {0,0,0,0,0,0,0,0};
        if (e1 < EE && ln < 4) {
            const u16* qr = g_qpi + (size_t)e1 * 256 + ln * 64;
            nqb0 = *(const s16x8*)(qr + q * 8);
            nqb1 = *(const s16x8*)(qr + 32 + q * 8);
        }
        float s[4];
#pragma unroll
        for (int r = 0; r < 4; r++) {
            int j = q * 4 + r;
            int ijj = __shfl(kv0, j);
            int jj = __shfl(kv0, 16 + j);
            float bvl = (ijj >= 0 && ln < 4) ? g_b4[(size_t)jj * 4 + ln] : 0.f;
            s[r] = (ijj >= 0) ? (0.125f * sc[r] + bvl) : 0.f;
        }
        float mx = fmaxf(fmaxf(s[0], s[1]), fmaxf(s[2], s[3]));
        mx = fmaxf(mx, __shfl_xor(mx, 16));
        mx = fmaxf(mx, __shfl_xor(mx, 32));
        float ex[4], ps = 0.f;
#pragma unroll
        for (int r = 0; r < 4; r++) { ex[r] = __expf(s[r] - mx); ps += ex[r]; }
        ps += __shfl_xor(ps, 16);
        ps += __shfl_xor(ps, 32);
        float inv = 1.f / ps;
        if (ln < 4)
            *(f32x4*)&sA[w][ln][q * 4] = (f32x4){ex[0] * inv, ex[1] * inv, ex[2] * inv, ex[3] * inv};
        asm volatile("s_waitcnt lgkmcnt(0)" ::: "memory");
        float t0 = 0.f, t1 = 0.f, t2 = 0.f, t3 = 0.f;
#pragma unroll
        for (int j4 = 0; j4 < 4; j4++) {
            f32x4 a0 = *(const f32x4*)&sA[w][0][j4 * 4];
            f32x4 a1 = *(const f32x4*)&sA[w][1][j4 * 4];
            f32x4 a2 = *(const f32x4*)&sA[w][2][j4 * 4];
            f32x4 a3 = *(const f32x4*)&sA[w][3][j4 * 4];
#pragma unroll
            for (int r = 0; r < 4; r++) {
                float zz = us2f(zw[(j4 * 4 + r) * 72 + lane]);
                t0 += a0[r] * zz; t1 += a1[r] * zz; t2 += a2[r] * zz; t3 += a3[r] * zz;
            }
        }
        size_t ob = (size_t)e0 * 64 + lane;
        g_t4[0][ob] = f2bu(t0);
        g_t4[1][ob] = f2bu(t1);
        g_t4[2][ob] = f2bu(t2);
        g_t4[3][ob] = f2bu(t3);
        if (e1 >= EE) break;
        e0 = e1; kv0 = kv1;
        e1 = e2; kv1 = kv2;
        za0 = nza0; za1 = nza1; qb0 = nqb0; qb1 = nqb1;
    }
}

// ---------------- fused heads: u=(t@Wv)*sigm(z@Wg+bg); m=Σ_hd u@oW_hd; single tile ----------------
__global__ __launch_bounds__(256) void k_us(
    const float* __restrict__ Wv, const float* __restrict__ Wg, const float* __restrict__ bg,
    const float* __restrict__ oW, const int* __restrict__ edges)
{
    __shared__ u16 sV[64 * 72], sO[64 * 72], sG[64 * 72];
    __shared__ u16 sU[4][16 * 72];
    int tid = threadIdx.x;
    int lane = tid & 63, q = lane >> 4, ln = lane & 15, w = tid >> 6;
    int m0 = blockIdx.x * 64 + w * 16;
    const u16* zr = g_z16 + (size_t)(m0 + ln) * 64;
    s16x8 za[2];
    za[0] = *(const s16x8*)(zr + q * 8);
    za[1] = *(const s16x8*)(zr + 32 + q * 8);
    f32x4 macc[4];
#pragma unroll
    for (int t = 0; t < 4; t++) macc[t] = (f32x4){0,0,0,0};
    for (int hd = 0; hd < 4; hd++) {
        if (hd) __syncthreads();
        stageW(sV, Wv + (size_t)hd * 4096, tid);
        stageW(sO, oW + (size_t)hd * 4096, tid);
        stageW(sG, Wg + (size_t)hd * 4096, tid);
        __syncthreads();
        f32x4 vacc[4], gacc[4];
#pragma unroll
        for (int t = 0; t < 4; t++) { vacc[t] = (f32x4){0,0,0,0}; gacc[t] = (f32x4){0,0,0,0}; }
        const u16* ar = &g_t4[hd][(size_t)(m0 + ln) * 64];
#pragma unroll
        for (int k0 = 0; k0 < 2; k0++) {
            s16x8 af = *(const s16x8*)(ar + k0 * 32 + q * 8);
#pragma unroll
            for (int t = 0; t < 4; t++) {
                vacc[t] = __builtin_amdgcn_mfma_f32_16x16x32_bf16(
                    af, *(const s16x8*)(&sV[(t * 16 + ln) * 72 + k0 * 32 + q * 8]), vacc[t], 0, 0, 0);
                gacc[t] = __builtin_amdgcn_mfma_f32_16x16x32_bf16(
                    za[k0], *(const s16x8*)(&sG[(t * 16 + ln) * 72 + k0 * 32 + q * 8]), gacc[t], 0, 0, 0);
            }
        }
#pragma unroll
        for (int t = 0; t < 4; t++) {
            float bb = bg[hd * 64 + t * 16 + ln];
#pragma unroll
            for (int r = 0; r < 4; r++) {
                float u = vacc[t][r] * sigmf(gacc[t][r] + bb);
                sU[w][(q * 4 + r) * 72 + t * 16 + ln] = f2bu(u);
            }
        }
        asm volatile("s_waitcnt lgkmcnt(0)" ::: "memory");
#pragma unroll
        for (int k0 = 0; k0 < 2; k0++) {
            s16x8 af = *(const s16x8*)(&sU[w][ln * 72 + k0 * 32 + q * 8]);
#pragma unroll
            for (int t = 0; t < 4; t++) {
                macc[t] = __builtin_amdgcn_mfma_f32_16x16x32_bf16(
                    af, *(const s16x8*)(&sO[(t * 16 + ln) * 72 + k0 * 32 + q * 8]), macc[t], 0, 0, 0);
            }
        }
    }
#pragma unroll
    for (int r = 0; r < 4; r++) {
        int dst = edges[m0 + q * 4 + r] * 64;
#pragma unroll
        for (int t = 0; t < 4; t++) atomicAdd(&g_msum[dst + t * 16 + ln], macc[t][r]);
    }
}

// ---------------- node finalize ----------------
__global__ __launch_bounds__(256) void k_node(
    const float* __restrict__ h, const float* __restrict__ na,
    const float* __restrict__ coord, const float* __restrict__ nvecs,
    const float* __restrict__ icoord, const float* __restrict__ invecs,
    const float* __restrict__ ob,
    const float* __restrict__ W1, const float* __restrict__ b1,
    const float* __restrict__ W2, const float* __restrict__ b2,
    float* __restrict__ out)
{
    __shared__ u16 sW1[192 * 64], sW2[4096];
    __shared__ float sb1[64], sb2[64];
    int tid = threadIdx.x;
    for (int i = tid; i < 192 * 64; i += 256) sW1[i] = f2bu(W1[i]);
    for (int i = tid; i < 4096; i += 256) sW2[i] = f2bu(W2[i]);
    if (tid < 64) { sb1[tid] = b1[tid]; sb2[tid] = b2[tid]; }
    __syncthreads();
    size_t coff = (size_t)NN * 64;
    size_t noff = coff + (size_t)NN * 3;
    int lane = tid & 63;
    int wid = blockIdx.x * 4 + (tid >> 6);
    int nw = gridDim.x * 4;
    for (int n = wid; n < NN; n += nw) {
        float craw = g_cnt[n];
        float rinv = 1.f / fmaxf(craw, 1.f);
        float hl = h[(size_t)n * 64 + lane];
        float al = na[(size_t)n * 64 + lane];
        float obv = (craw > 0.f) ? ob[lane] : 0.f;
        float ml = g_msum[n * 64 + lane] * rinv + obv;
        float acc = sb1[lane];
        for (int i = 0; i < 64; i++) acc += __shfl(hl, i) * us2f(sW1[i * 64 + lane]);
        for (int i = 0; i < 64; i++) acc += __shfl(al, i) * us2f(sW1[(64 + i) * 64 + lane]);
        for (int i = 0; i < 64; i++) acc += __shfl(ml, i) * us2f(sW1[(128 + i) * 64 + lane]);
        float t = siluf(acc);
        float a2 = sb2[lane];
        for (int i = 0; i < 64; i++) a2 += __shfl(t, i) * us2f(sW2[i * 64 + lane]);
        out[(size_t)n * 64 + lane] = 0.2f * hl + 0.8f * a2;
        if (lane < 3) {
            out[coff + n * 3 + lane] = 0.2f * icoord[n * 3 + lane] + 0.8f * coord[n * 3 + lane]
                                       + g_xsum[n * 3 + lane] * rinv;
        }
        float nl = (lane < 3)
            ? (0.2f * invecs[n * 3 + lane] + 0.8f * nvecs[n * 3 + lane] + g_nsum[n * 3 + lane] * rinv)
            : 0.f;
        float nn = sqrtf(waveSum(nl * nl)) + 1e-8f;
        if (lane < 3) out[noff + n * 3 + lane] = nl / nn;
    }
}

extern "C" void kernel_launch(void* const* d_in, const int* in_sizes, int n_in,
                              void* d_out, int out_size, void* d_ws, size_t ws_size,
                              hipStream_t stream)
{
    const int* edges = (const int*)d_in[43];
    const int* klist = (const int*)d_in[44];
    auto F = [&](int i) { return (const float*)d_in[i]; };

    k_prep<<<512, 256, 0, stream>>>(F(19), F(20), F(0), F(4), F(3), F(1), F(2), edges);
    k_chem1<<<1563, 256, 0, stream>>>(edges, F(7), F(8));
    k_megaAB<<<1563, 256, 0, stream>>>(F(9), F(10), F(11), F(12), F(13), F(14),
                                       F(15), F(16), F(17), F(18), F(22),
                                       F(27), F(28), F(29), F(30),
                                       F(31), F(32), F(33), F(34),
                                       F(35), F(36), F(37), F(38),
                                       edges, F(2));
    k_q4<<<1563, 256, 0, stream>>>();
    k_attn2<<<2048, 256, 0, stream>>>(klist);
    k_us<<<3125, 256, 0, stream>>>(F(21), F(23), F(24), F(25), edges);
    k_node<<<640, 256, 0, stream>>>(F(0), F(4), F(1), F(2), F(5), F(6), F(26),
                                    F(39), F(40), F(41), F(42), (float*)d_out);
}